// Round 1
// baseline (1394.043 us; speedup 1.0000x reference)
//
#include <hip/hip_runtime.h>
#include <math.h>

typedef unsigned long long u64;
typedef unsigned int u32;

// Problem constants
#define L 512
#define E 300
#define H 512          // per-direction hidden
#define G4H 2048       // 4*H
#define NTAGS 20
#define START_TAG 18
#define STOP_TAG 19

#define KC 100         // k1 K-chunk (300 = 3*100)

// Workspace layout (bytes)
#define OFF_XW    0u          // f32 [2][512][2048] (permuted cols) = 8388608
#define OFF_HIST  8388608u    // f32 [2][512][512]  = 2097152
#define OFF_HBUF  10485760u   // u64 [2][2][512]    = 16384
#define OFF_FEATS 10502144u   // f32 [512][20]      = 40960

// ---------------------------------------------------------------------------
// K1: tiled GEMM  xw[dir][t][pos(n)] = embed[sent[t]] . wih[n] + bias(n).
// 64n x 64t tile, 4x4 microtile, K chunks of 100 staged in LDS.
// pos(n) gate-major within each k2 WG's 64-block: u=n&511, g=n>>9 ->
// pos = (u>>4)*64 + g*16 + (u&15)  -> k2 wave0 tail reads xw[t][wg*64+l].
__global__ __launch_bounds__(256) void k1_xw(
    const int* __restrict__ sentence, const float* __restrict__ embed,
    const float* __restrict__ wih_f, const float* __restrict__ wih_b,
    const float* __restrict__ bih_f, const float* __restrict__ bhh_f,
    const float* __restrict__ bih_b, const float* __restrict__ bhh_b,
    float* __restrict__ xw) {
    __shared__ float wST[KC][68];   // [k][n]
    __shared__ float xST[KC][68];   // [k][t]
    __shared__ int   sT[64];

    const int tid = threadIdx.x;
    const int tx = tid & 15;        // t micro index
    const int ty = tid >> 4;        // n micro index
    const int n_base = blockIdx.x * 64;
    const int t_base = blockIdx.y * 64;
    const int dir = blockIdx.z;
    const float* wih = dir ? wih_b : wih_f;
    const float* bih = dir ? bih_b : bih_f;
    const float* bhh = dir ? bhh_b : bhh_f;

    if (tid < 64) sT[tid] = sentence[t_base + tid];
    __syncthreads();

    float acc[4][4];
#pragma unroll
    for (int i = 0; i < 4; ++i)
#pragma unroll
        for (int j = 0; j < 4; ++j) acc[i][j] = 0.f;

    for (int kc = 0; kc < E; kc += KC) {
#pragma unroll
        for (int i = 0; i < 25; ++i) {
            int idx = i * 256 + tid;          // < 6400
            int row = idx / KC, col = idx % KC;
            wST[col][row] = wih[(size_t)(n_base + row) * E + kc + col];
        }
#pragma unroll
        for (int i = 0; i < 25; ++i) {
            int idx = i * 256 + tid;
            int trow = idx / KC, col = idx % KC;
            xST[col][trow] = embed[(size_t)sT[trow] * E + kc + col];
        }
        __syncthreads();

#pragma unroll 4
        for (int k = 0; k < KC; ++k) {
            float4 wv4 = *(const float4*)&wST[k][ty * 4];
            float4 xv4 = *(const float4*)&xST[k][tx * 4];
            float wv[4] = {wv4.x, wv4.y, wv4.z, wv4.w};
            float xv[4] = {xv4.x, xv4.y, xv4.z, xv4.w};
#pragma unroll
            for (int i = 0; i < 4; ++i)
#pragma unroll
                for (int j = 0; j < 4; ++j)
                    acc[i][j] = fmaf(wv[i], xv[j], acc[i][j]);
        }
        __syncthreads();
    }

#pragma unroll
    for (int i = 0; i < 4; ++i) {
        int n = n_base + ty * 4 + i;
        float b = bih[n] + bhh[n];
        int u = n & (H - 1), g = n >> 9;
        int pos = (u >> 4) * 64 + g * 16 + (u & 15);   // gate-major in block
#pragma unroll
        for (int j = 0; j < 4; ++j) {
            int t = t_base + tx * 4 + j;
            xw[((size_t)(dir * L) + t) * G4H + pos] = acc[i][j] + b;
        }
    }
}

// ---------------------------------------------------------------------------
// K2: bidirectional LSTM recurrence. 64 WGs x 512 threads (r3 skeleton).
// Thread tid polls slot 'tid' (3-deep pipelined -> sampling ~RT/3).
// Wave wv holds h[64wv..64wv+64) in-lane -> readlane dot (4 split accs),
// lane l = gate-major row (g=l>>4, j=l&15). Cross-wave reduce via pbuf +
// ONE barrier; wave0 funnel tail: gates + single coalesced 128B publish.
// __launch_bounds__(512, 1): only 64 WGs on 256 CUs -> occupancy is
// irrelevant; relax the VGPR budget so w[64] stays register-resident
// (at (512) default the compiler granted 48 VGPRs and re-fetched the
// weight slice from memory EVERY step, on the serial critical path).
__global__ __launch_bounds__(512, 1) void k2_lstm(
    const float* __restrict__ whh_f, const float* __restrict__ whh_b,
    const float* __restrict__ h0, const float* __restrict__ c0,
    const float* __restrict__ xw, float* __restrict__ hist,
    u64* __restrict__ hbuf) {
    const int bid = blockIdx.x;
    const int dir = bid >> 5;
    const int wg  = bid & 31;
    const int tid = threadIdx.x;
    const int wv  = tid >> 6;       // wave id = dot k-slice
    const int l   = tid & 63;
    const int g   = l >> 4;         // gate: 0=i 1=f 2=g 3=o
    const int j   = l & 15;         // unit within WG
    const int grow = g * H + wg * 16 + j;

    const float* whh = dir ? whh_b : whh_f;
    float* histd = hist + (size_t)dir * L * H;
    u64* hb = hbuf + dir * 1024;    // [parity][512]

    // this lane's 64 Whh weights (row grow, slice wv) -> VGPRs
    float w[64];
    {
        const float* wp = whh + (size_t)grow * H + wv * 64;
#pragma unroll
        for (int i = 0; i < 64; i += 4) {
            float4 v = *(const float4*)(wp + i);
            w[i] = v.x; w[i+1] = v.y; w[i+2] = v.z; w[i+3] = v.w;
        }
    }

    __shared__ float pbuf[2][8][68];   // [parity][slice][row(+pad)]

    // c state lives on wave0 lanes 0..15 (unit = wg*16 + tid)
    float c = (tid < 16) ? c0[dir * H + wg * 16 + tid] : 0.f;

    for (int s = 1; s <= L; ++s) {
        const int t = dir ? (L - s) : (s - 1);
        const int par = s & 1;

        // xw for wave0's tail rows: coalesced 64-lane load (gate-major layout)
        float xwv = 0.f;
        if (tid < 64)
            xwv = xw[((size_t)(dir * L) + t) * G4H + wg * 64 + l];

        // ---- acquire h_{s-1}[tid]: 3-deep pipelined poll on own slot ----
        float hval;
        if (s == 1) {
            hval = h0[dir * H + tid];
        } else {
            const u32 want = (u32)(s - 1);
            u64* slot = hb + ((s - 1) & 1) * 512 + tid;
            u64 v0 = __hip_atomic_load(slot, __ATOMIC_RELAXED, __HIP_MEMORY_SCOPE_AGENT);
            u64 v1 = __hip_atomic_load(slot, __ATOMIC_RELAXED, __HIP_MEMORY_SCOPE_AGENT);
            u64 v2 = __hip_atomic_load(slot, __ATOMIC_RELAXED, __HIP_MEMORY_SCOPE_AGENT);
            while ((u32)(v0 >> 32) != want) {
                v0 = v1; v1 = v2;
                v2 = __hip_atomic_load(slot, __ATOMIC_RELAXED, __HIP_MEMORY_SCOPE_AGENT);
            }
            hval = __uint_as_float((u32)v0);
        }

        // ---- dot: row l over slice wv via readlane broadcast, 4 accs ----
        float a0 = 0.f, a1 = 0.f, a2 = 0.f, a3 = 0.f;
#pragma unroll
        for (int i = 0; i < 64; i += 4) {
            float h0v = __uint_as_float((u32)__builtin_amdgcn_readlane(
                            (int)__float_as_uint(hval), i));
            float h1v = __uint_as_float((u32)__builtin_amdgcn_readlane(
                            (int)__float_as_uint(hval), i + 1));
            float h2v = __uint_as_float((u32)__builtin_amdgcn_readlane(
                            (int)__float_as_uint(hval), i + 2));
            float h3v = __uint_as_float((u32)__builtin_amdgcn_readlane(
                            (int)__float_as_uint(hval), i + 3));
            a0 = fmaf(w[i],     h0v, a0);
            a1 = fmaf(w[i + 1], h1v, a1);
            a2 = fmaf(w[i + 2], h2v, a2);
            a3 = fmaf(w[i + 3], h3v, a3);
        }
        pbuf[par][wv][l] = (a0 + a1) + (a2 + a3);
        __syncthreads();

        // ---- wave0 funnel tail: reduce 8 partials, gates, publish ----
        if (tid < 64) {
            float tot = 0.f;
#pragma unroll
            for (int p = 0; p < 8; ++p) tot += pbuf[par][p][l];
            float pre = tot + xwv;
            float aa = (g == 2) ? 2.f * pre : pre;       // tanh = 2*sig(2x)-1
            float sg = 1.f / (1.f + __expf(-aa));
            float vg = (g == 2) ? (2.f * sg - 1.f) : sg;
            float gi = __shfl(vg, j);
            float gf = __shfl(vg, 16 + j);
            float gg = __shfl(vg, 32 + j);
            float go = __shfl(vg, 48 + j);
            if (tid < 16) {
                c = gf * c + gi * gg;
                float th = 2.f / (1.f + __expf(-2.f * c)) - 1.f;
                float hout = go * th;
                // single coalesced 128B publish (16 lanes x 8B, contiguous)
                u64 e = ((u64)(u32)s << 32) | (u64)__float_as_uint(hout);
                __hip_atomic_store(hb + par * 512 + wg * 16 + tid, e,
                                   __ATOMIC_RELAXED, __HIP_MEMORY_SCOPE_AGENT);
                histd[(size_t)t * H + wg * 16 + tid] = hout;
            }
        }
        // pbuf parity double-buffer + the single barrier covers reuse
    }
}

// ---------------------------------------------------------------------------
// K3: feats[t][tag] = b_out[tag] + concat(hf,hb)[t] . w_out[tag]   (f32)
__global__ void k3_feats(const float* __restrict__ hist,
                         const float* __restrict__ wout,
                         const float* __restrict__ bout,
                         float* __restrict__ feats) {
    int t = blockIdx.x;
    int tid = threadIdx.x;
    int tag = tid >> 4;       // [0,20)
    int part = tid & 15;
    const float* h0p = hist + (size_t)t * H;
    const float* h1p = hist + (size_t)L * H + (size_t)t * H;
    int j0 = part * 64;
    float acc = 0.f;
    for (int jj = 0; jj < 64; jj += 4) {
        int j = j0 + jj;
        float4 w4 = *(const float4*)(wout + (size_t)tag * (2 * H) + j);
        float4 h4 = (j < H) ? *(const float4*)(h0p + j)
                            : *(const float4*)(h1p + (j - H));
        acc = fmaf(w4.x, h4.x, fmaf(w4.y, h4.y,
              fmaf(w4.z, h4.z, fmaf(w4.w, h4.w, acc))));
    }
    acc += __shfl_xor(acc, 8, 16);
    acc += __shfl_xor(acc, 4, 16);
    acc += __shfl_xor(acc, 2, 16);
    acc += __shfl_xor(acc, 1, 16);
    if (part == 0) feats[(size_t)t * NTAGS + tag] = acc + bout[tag];
}

// ---------------------------------------------------------------------------
// K4: Viterbi + backtrack, one wave. Batched shfls + index-carrying tree-max
// (exact first-max semantics).
__global__ void k4_viterbi(const float* __restrict__ feats,
                           const float* __restrict__ trans,
                           int* __restrict__ out) {
    __shared__ unsigned char bp[L * NTAGS];
    int lane = threadIdx.x;           // 64 threads
    bool act = lane < NTAGS;

    float trl[NTAGS];
#pragma unroll
    for (int p = 0; p < NTAGS; ++p)
        trl[p] = act ? trans[lane * NTAGS + p] : -1.0e30f;

    float fv = (lane == START_TAG) ? 0.f : -10000.f;
    float nf = act ? feats[lane] : 0.f;

    for (int t = 0; t < L; ++t) {
        float f = nf;
        if (act && t + 1 < L) nf = feats[(size_t)(t + 1) * NTAGS + lane];
        float tv[NTAGS];
        int   ti[NTAGS];
#pragma unroll
        for (int p = 0; p < NTAGS; ++p) {
            tv[p] = __shfl(fv, p) + trl[p];
            ti[p] = p;
        }
#pragma unroll
        for (int p = 0; p < 4; ++p) {
            bool take = (tv[p + 16] > tv[p]) ||
                        (tv[p + 16] == tv[p] && ti[p + 16] < ti[p]);
            if (take) { tv[p] = tv[p + 16]; ti[p] = ti[p + 16]; }
        }
#pragma unroll
        for (int w = 8; w >= 1; w >>= 1)
#pragma unroll
            for (int p = 0; p < 16; ++p) if (p < w) {
                bool take = (tv[p + w] > tv[p]) ||
                            (tv[p + w] == tv[p] && ti[p + w] < ti[p]);
                if (take) { tv[p] = tv[p + w]; ti[p] = ti[p + w]; }
            }
        fv = tv[0] + f;
        if (act) bp[t * NTAGS + lane] = (unsigned char)ti[0];
    }

    float ts = act ? fv + trans[STOP_TAG * NTAGS + lane] : -1.0e30f;
    int bi = lane;
#pragma unroll
    for (int off = 32; off; off >>= 1) {
        float ov = __shfl_down(ts, off);
        int   oi = __shfl_down(bi, off);
        if (ov > ts) { ts = ov; bi = oi; }
    }
    if (lane == 0) {
        int tag = bi;
        out[L - 1] = tag;
        for (int t = L - 1; t >= 1; --t) {
            tag = bp[t * NTAGS + tag];
            out[t - 1] = tag;
        }
    }
}

// ---------------------------------------------------------------------------
extern "C" void kernel_launch(void* const* d_in, const int* in_sizes, int n_in,
                              void* d_out, int out_size, void* d_ws, size_t ws_size,
                              hipStream_t stream) {
    const int*   sentence = (const int*)d_in[0];
    const float* embed    = (const float*)d_in[1];
    const float* wih_f    = (const float*)d_in[2];
    const float* whh_f    = (const float*)d_in[3];
    const float* bih_f    = (const float*)d_in[4];
    const float* bhh_f    = (const float*)d_in[5];
    const float* wih_b    = (const float*)d_in[6];
    const float* whh_b    = (const float*)d_in[7];
    const float* bih_b    = (const float*)d_in[8];
    const float* bhh_b    = (const float*)d_in[9];
    const float* h0       = (const float*)d_in[10];
    const float* c0       = (const float*)d_in[11];
    const float* wout     = (const float*)d_in[12];
    const float* bout     = (const float*)d_in[13];
    const float* trans    = (const float*)d_in[14];
    int* out = (int*)d_out;

    char* ws = (char*)d_ws;
    float* xw    = (float*)(ws + OFF_XW);
    float* hist  = (float*)(ws + OFF_HIST);
    float* feats = (float*)(ws + OFF_FEATS);
    u64*   hbuf  = (u64*)(ws + OFF_HBUF);

    k1_xw<<<dim3(32, 8, 2), 256, 0, stream>>>(sentence, embed, wih_f, wih_b,
                                              bih_f, bhh_f, bih_b, bhh_b, xw);
    k2_lstm<<<64, 512, 0, stream>>>(whh_f, whh_b, h0, c0, xw, hist, hbuf);
    k3_feats<<<L, 320, 0, stream>>>(hist, wout, bout, feats);
    k4_viterbi<<<1, 64, 0, stream>>>(feats, trans, out);
}